// Round 15
// baseline (2157.390 us; speedup 1.0000x reference)
//
#include <hip/hip_runtime.h>
#include <hip/hip_bf16.h>
#include <math.h>

#define VSZ 2048
#define EDIM 256
#define HDIM 256
#define G4 1024   // 4*H
#define TMAX 16
#define IB 16     // instructions per workgroup in token-LSTM (MFMA M=16)

typedef _Float16 f16x2 __attribute__((ext_vector_type(2)));
typedef _Float16 f16x4 __attribute__((ext_vector_type(4)));
typedef _Float16 f16x8 __attribute__((ext_vector_type(8)));
typedef float f32x4 __attribute__((ext_vector_type(4)));

#define HA_STRIDE 264   // fp16 elems per hA row (256 + 8 pad)
#define GW_STRIDE 260   // fp32 elems per gateW row (256 + 4 pad)

__device__ __forceinline__ float sigm(float x) { return 1.0f / (1.0f + expf(-x)); }

__device__ __forceinline__ float fdot2(f16x2 a, f16x2 b, float c) {
#if defined(__has_builtin) && __has_builtin(__builtin_amdgcn_fdot2)
  return __builtin_amdgcn_fdot2(a, b, c, false);
#else
  return c + (float)a.x * (float)b.x + (float)a.y * (float)b.y;
#endif
}

__device__ __forceinline__ float dot8h(uint4 w, float4 hv, float acc) {
  f16x2 h0 = __builtin_bit_cast(f16x2, hv.x);
  f16x2 h1 = __builtin_bit_cast(f16x2, hv.y);
  f16x2 h2 = __builtin_bit_cast(f16x2, hv.z);
  f16x2 h3 = __builtin_bit_cast(f16x2, hv.w);
  f16x2 w0 = __builtin_bit_cast(f16x2, w.x);
  f16x2 w1 = __builtin_bit_cast(f16x2, w.y);
  f16x2 w2 = __builtin_bit_cast(f16x2, w.z);
  f16x2 w3 = __builtin_bit_cast(f16x2, w.w);
  return fdot2(h3, w3, fdot2(h2, w2, fdot2(h1, w1, fdot2(h0, w0, acc))));
}

// ---- dtype probes ----
__device__ __forceinline__ bool is_f32(const void* w) {
  const unsigned short* p = (const unsigned short*)w;
  int pl = 0;
#pragma unroll
  for (int i = 0; i < 64; ++i) {
    unsigned e = (p[2 * i] >> 7) & 0xFF;
    pl += (e >= 113 && e <= 122) ? 1 : 0;
  }
  return pl < 48;
}

// ---- typed loads ----
template <bool F32>
__device__ __forceinline__ float ldf(const void* p, long j) {
  if (F32) return ((const float*)p)[j];
  return __uint_as_float(((unsigned)((const unsigned short*)p)[j]) << 16);
}
__device__ __forceinline__ float ldf_rt(const void* p, long j, bool f32) {
  if (f32) return ((const float*)p)[j];
  return __uint_as_float(((unsigned)((const unsigned short*)p)[j]) << 16);
}
template <bool I64>
__device__ __forceinline__ int ldi(const int* p, int j) {
  return I64 ? p[2 * j] : p[j];
}
__device__ __forceinline__ int ldi_rt(const int* p, int j, bool i64) {
  return i64 ? p[2 * j] : p[j];
}

// ===== fp32 transpose: dst[k*1024 + r] = src[r*256 + k] =====
__global__ __launch_bounds__(256) void k_transp(const void* src, float* __restrict__ dst,
                                                const void* fprobe) {
  __shared__ float tile[32][33];
  __shared__ int sf;
  if (threadIdx.x == 0) sf = is_f32(fprobe) ? 1 : 0;
  __syncthreads();
  const bool f32 = (sf != 0);
  const int tx = threadIdx.x & 31, ty = threadIdx.x >> 5;
  const int r0 = blockIdx.x * 32, c0 = blockIdx.y * 32;
#pragma unroll
  for (int q = 0; q < 4; ++q) {
    int rr = ty + q * 8;
    tile[rr][tx] = ldf_rt(src, (long)(r0 + rr) * 256 + (c0 + tx), f32);
  }
  __syncthreads();
#pragma unroll
  for (int q = 0; q < 4; ++q) {
    int cc = ty + q * 8;
    dst[(size_t)(c0 + cc) * 1024 + (r0 + tx)] = tile[tx][cc];
  }
}

// ===== fp16 weight packing (row-gang layout for k_ins_rec) =====
__global__ __launch_bounds__(256) void k_pack(const void* src, uint4* __restrict__ dst,
                                              const void* fprobe) {
  __shared__ int sf;
  if (threadIdx.x == 0) sf = is_f32(fprobe) ? 1 : 0;
  __syncthreads();
  const bool f32 = (sf != 0);
  const int idx = blockIdx.x * 256 + threadIdx.x;  // grid 128
  const int rr = idx & 255, j = (idx >> 8) & 3, c = idx >> 10;
  const long base = (long)(j * 256 + rr) * 256 + 8 * c;
  unsigned u[4];
#pragma unroll
  for (int q = 0; q < 4; ++q) {
    f16x2 v;
    v.x = (_Float16)ldf_rt(src, base + 2 * q, f32);
    v.y = (_Float16)ldf_rt(src, base + 2 * q + 1, f32);
    u[q] = __builtin_bit_cast(unsigned, v);
  }
  uint4 o; o.x = u[0]; o.y = u[1]; o.z = u[2]; o.w = u[3];
  dst[idx] = o;
}

// ===== MFMA B-fragment packing (gate col n = e*4 + j) =====
__global__ __launch_bounds__(256) void k_packB(const void* src, f16x8* __restrict__ dst,
                                               const void* fprobe) {
  __shared__ int sf;
  if (threadIdx.x == 0) sf = is_f32(fprobe) ? 1 : 0;
  __syncthreads();
  const bool f32 = (sf != 0);
  const int idx = blockIdx.x * 256 + threadIdx.x;  // 0..32767, grid 128
  const int l = idx & 63;
  int rest = idx >> 6;
  const int kt = rest & 7; rest >>= 3;
  const int nt = rest & 15;
  const int w = rest >> 4;
  const int n = 256 * w + nt * 16 + (l & 15);
  const int j = n & 3, e = n >> 2;
  const long base = (long)(j * 256 + e) * 256 + kt * 32 + ((l >> 4) << 3);
  f16x8 v;
#pragma unroll
  for (int q = 0; q < 8; ++q) v[q] = (_Float16)ldf_rt(src, base + q, f32);
  dst[idx] = v;
}

// ===== kernel 1: token gate table -> interleaved fp16x4 tab =====
template <bool F32>
__device__ void tok_table_impl(const void* emb, const float* __restrict__ wT,
                               const void* bih, const void* bhh,
                               f16x4* __restrict__ tabi4, float (*xs)[256]) {
  const int t = threadIdx.x;
  const int v0 = blockIdx.x * 16;
#pragma unroll
  for (int i = 0; i < 16; ++i) xs[i][t] = ldf<F32>(emb, (long)(v0 + i) * EDIM + t);
  __syncthreads();
  float acc[4][16];
#pragma unroll
  for (int j = 0; j < 4; ++j)
#pragma unroll
    for (int i = 0; i < 16; ++i) acc[j][i] = 0.f;
  for (int k4 = 0; k4 < 64; ++k4) {
    float w[4][4];
#pragma unroll
    for (int kk = 0; kk < 4; ++kk)
#pragma unroll
      for (int j = 0; j < 4; ++j)
        w[j][kk] = wT[(size_t)(k4 * 4 + kk) * 1024 + j * 256 + t];
#pragma unroll
    for (int i = 0; i < 16; ++i) {
      float4 h4 = *(const float4*)&xs[i][k4 * 4];
#pragma unroll
      for (int j = 0; j < 4; ++j)
        acc[j][i] = fmaf(h4.x, w[j][0], fmaf(h4.y, w[j][1],
                    fmaf(h4.z, w[j][2], fmaf(h4.w, w[j][3], acc[j][i]))));
    }
  }
  float b[4];
#pragma unroll
  for (int j = 0; j < 4; ++j)
    b[j] = ldf<F32>(bih, j * 256 + t) + ldf<F32>(bhh, j * 256 + t);
#pragma unroll
  for (int i = 0; i < 16; ++i) {
    f16x4 v;
    v.x = (_Float16)(acc[0][i] + b[0]);
    v.y = (_Float16)(acc[1][i] + b[1]);
    v.z = (_Float16)(acc[2][i] + b[2]);
    v.w = (_Float16)(acc[3][i] + b[3]);
    tabi4[(size_t)(v0 + i) * 256 + t] = v;
  }
}

__global__ __launch_bounds__(256) void k_tok_table(
    const void* emb, const float* __restrict__ wT, const void* bih,
    const void* bhh, f16x4* __restrict__ tabi4, const void* fprobe) {
  __shared__ float xs[16][256];
  __shared__ int sf;
  if (threadIdx.x == 0) sf = is_f32(fprobe) ? 1 : 0;
  __syncthreads();
  if (sf) tok_table_impl<true>(emb, wT, bih, bhh, tabi4, xs);
  else    tok_table_impl<false>(emb, wT, bih, bhh, tabi4, xs);
}

// ===== length bucketing: single WG, LDS atomics only =====
__global__ __launch_bounds__(1024) void k_bucket(const int* tlen, int N,
                                                 int* __restrict__ perm,
                                                 const int* iprobe) {
  __shared__ int cnt[17], base[17], cur[17];
  const int t = threadIdx.x;
  const bool i64 = (iprobe[1] == 0);
  if (t < 17) { cnt[t] = 0; cur[t] = 0; }
  __syncthreads();
  for (int n = t; n < N; n += 1024) {
    int len = ldi_rt(tlen, n, i64);
    len = max(0, min(16, len));
    atomicAdd(&cnt[len], 1);
  }
  __syncthreads();
  if (t == 0) {
    int s = 0;
    for (int i = 0; i <= 16; ++i) { base[i] = s; s += cnt[i]; }
  }
  __syncthreads();
  for (int n = t; n < N; n += 1024) {
    int len = ldi_rt(tlen, n, i64);
    len = max(0, min(16, len));
    int pos = base[len] + atomicAdd(&cur[len], 1);
    perm[pos] = n;
  }
}

// ===== kernel 2: token LSTM — MFMA 16x16x32 f16, tab prefetch =====
struct TokSmemM {
  float gateW[4][16 * GW_STRIDE];   // 66560 B: per-wave D staging (fp32)
  _Float16 hA[16 * HA_STRIDE];      // 8448 B: h in MFMA-A layout (fp16)
  int tokL[IB][TMAX];
  int lenL[IB];
  int nIdx[IB];
};

template <bool I64>
__device__ void tok_mfma_impl(const int* tok32, const int* tlen32,
                              const int* __restrict__ perm,
                              const f16x4* __restrict__ tabi4,
                              const f16x8* __restrict__ pkB,
                              float* __restrict__ instrH, int N, TokSmemM& sm) {
  const int n0 = blockIdx.x * IB, t = threadIdx.x;
  const int w = t >> 6, l = t & 63;
  if (t < IB) {
    int slot = n0 + t;
    int n = (slot < N) ? perm[slot] : -1;
    sm.nIdx[t] = n;
    sm.lenL[t] = (n >= 0) ? ldi<I64>(tlen32, n) : 0;
  }
  for (int idx = t; idx < 16 * HA_STRIDE / 2; idx += 256) ((unsigned*)sm.hA)[idx] = 0;
  __syncthreads();
  {
    int i = t >> 4, s = t & 15;
    int n = sm.nIdx[i];
    sm.tokL[i][s] = (n >= 0) ? ldi<I64>(tok32, n * TMAX + s) : 0;
  }
  float c[IB];
#pragma unroll
  for (int i = 0; i < IB; ++i) c[i] = 0.f;
  __syncthreads();
  int maxlen = 0;
#pragma unroll
  for (int i = 0; i < IB; ++i) maxlen = max(maxlen, sm.lenL[i]);

  const f16x8* Bp = pkB + (size_t)w * (16 * 8 * 64);
  const int aOff = (l & 15) * HA_STRIDE + ((l >> 4) << 3);
  const int m0 = (l >> 4) << 2;
  float* gw = sm.gateW[w];

  for (int s = 0; s < maxlen; ++s) {
    // PREFETCH: issue all 16 tab gathers now; they complete behind the MFMA
    // phase and the s_waitcnt lands after the barrier (latency hidden).
    f16x4 tb[IB];
#pragma unroll
    for (int m = 0; m < IB; ++m)
      tb[m] = tabi4[(size_t)sm.tokL[m][s] * 256 + t];
    f16x8 aF[8];
#pragma unroll
    for (int kt = 0; kt < 8; ++kt)
      aF[kt] = *(const f16x8*)&sm.hA[aOff + kt * 32];
#pragma unroll 2
    for (int g4 = 0; g4 < 4; ++g4) {
      f32x4 a0 = {0.f, 0.f, 0.f, 0.f}, a1 = a0, a2 = a0, a3 = a0;
#pragma unroll
      for (int kt = 0; kt < 8; ++kt) {
        const f16x8* bb = Bp + ((size_t)(g4 * 4) * 8 + kt) * 64 + l;
        f16x8 b0 = bb[0 * 8 * 64];
        f16x8 b1 = bb[1 * 8 * 64];
        f16x8 b2 = bb[2 * 8 * 64];
        f16x8 b3 = bb[3 * 8 * 64];
        a0 = __builtin_amdgcn_mfma_f32_16x16x32_f16(aF[kt], b0, a0, 0, 0, 0);
        a1 = __builtin_amdgcn_mfma_f32_16x16x32_f16(aF[kt], b1, a1, 0, 0, 0);
        a2 = __builtin_amdgcn_mfma_f32_16x16x32_f16(aF[kt], b2, a2, 0, 0, 0);
        a3 = __builtin_amdgcn_mfma_f32_16x16x32_f16(aF[kt], b3, a3, 0, 0, 0);
      }
      const int colb = (l & 15);
#pragma unroll
      for (int r = 0; r < 4; ++r) {
        gw[(m0 + r) * GW_STRIDE + (g4 * 4 + 0) * 16 + colb] = a0[r];
        gw[(m0 + r) * GW_STRIDE + (g4 * 4 + 1) * 16 + colb] = a1[r];
        gw[(m0 + r) * GW_STRIDE + (g4 * 4 + 2) * 16 + colb] = a2[r];
        gw[(m0 + r) * GW_STRIDE + (g4 * 4 + 3) * 16 + colb] = a3[r];
      }
    }
    __syncthreads();
#pragma unroll 4
    for (int m = 0; m < IB; ++m) {
      if (s < sm.lenL[m]) {
        float4 gv = *(const float4*)&gw[m * GW_STRIDE + 4 * l];
        float gi = gv.x + (float)tb[m].x;
        float gf = gv.y + (float)tb[m].y;
        float gg = gv.z + (float)tb[m].z;
        float go = gv.w + (float)tb[m].w;
        float si = sigm(gi), sf = sigm(gf), tg = tanhf(gg), so = sigm(go);
        c[m] = sf * c[m] + si * tg;
        sm.hA[m * HA_STRIDE + t] = (_Float16)(so * tanhf(c[m]));
      }
    }
    __syncthreads();
  }
#pragma unroll
  for (int m = 0; m < IB; ++m) {
    int n = sm.nIdx[m];
    if (n >= 0) instrH[(size_t)n * HDIM + t] = (float)sm.hA[m * HA_STRIDE + t];
  }
}

__global__ __launch_bounds__(256, 2) void k_tok_lstm(
    const int* tok32, const int* tlen32, const int* __restrict__ perm,
    const f16x4* __restrict__ tabi4, const f16x8* __restrict__ pkB,
    float* __restrict__ instrH, int N, const int* iprobe) {
  __shared__ TokSmemM sm;
  __shared__ int sfl;
  if (threadIdx.x == 0) sfl = (iprobe[1] == 0) ? 1 : 0;
  __syncthreads();
  if (sfl) tok_mfma_impl<true >(tok32, tlen32, perm, tabi4, pkB, instrH, N, sm);
  else     tok_mfma_impl<false>(tok32, tlen32, perm, tabi4, pkB, instrH, N, sm);
}

// ===== kernel 3a: gx GEMM (fp32) =====
template <bool F32>
__device__ void gx_impl(const float* __restrict__ instrH,
                        const float* __restrict__ wT, const void* bih,
                        const void* bhh, float* __restrict__ gx, int N,
                        float (*xs)[256]) {
  const int t = threadIdx.x;
  const int n0 = blockIdx.x * 16;
#pragma unroll
  for (int i = 0; i < 16; ++i) {
    int n = n0 + i;
    xs[i][t] = (n < N) ? instrH[(size_t)n * HDIM + t] : 0.f;
  }
  __syncthreads();
  float acc[4][16];
#pragma unroll
  for (int j = 0; j < 4; ++j)
#pragma unroll
    for (int i = 0; i < 16; ++i) acc[j][i] = 0.f;
  for (int k4 = 0; k4 < 64; ++k4) {
    float w[4][4];
#pragma unroll
    for (int kk = 0; kk < 4; ++kk)
#pragma unroll
      for (int j = 0; j < 4; ++j)
        w[j][kk] = wT[(size_t)(k4 * 4 + kk) * 1024 + j * 256 + t];
#pragma unroll
    for (int i = 0; i < 16; ++i) {
      float4 h4 = *(const float4*)&xs[i][k4 * 4];
#pragma unroll
      for (int j = 0; j < 4; ++j)
        acc[j][i] = fmaf(h4.x, w[j][0], fmaf(h4.y, w[j][1],
                    fmaf(h4.z, w[j][2], fmaf(h4.w, w[j][3], acc[j][i]))));
    }
  }
#pragma unroll
  for (int j = 0; j < 4; ++j) {
    const float bj = ldf<F32>(bih, j * 256 + t) + ldf<F32>(bhh, j * 256 + t);
#pragma unroll
    for (int i = 0; i < 16; ++i) {
      int n = n0 + i;
      if (n < N) gx[(size_t)n * G4 + j * 256 + t] = acc[j][i] + bj;
    }
  }
}

__global__ __launch_bounds__(256) void k_gx(
    const float* __restrict__ instrH, const float* __restrict__ wT,
    const void* bih, const void* bhh, float* __restrict__ gx, int N,
    const void* fprobe) {
  __shared__ float xs[16][256];
  __shared__ int sf;
  if (threadIdx.x == 0) sf = is_f32(fprobe) ? 1 : 0;
  __syncthreads();
  if (sf) gx_impl<true>(instrH, wT, bih, bhh, gx, N, xs);
  else    gx_impl<false>(instrH, wT, bih, bhh, gx, N, xs);
}

// ===== kernel 3b: instruction-LSTM — weights RESIDENT in regs+LDS =====
#define RCH 24   // chunks in registers
#define LCH 8    // chunks in LDS
struct InsSmem {
  uint4 wL[LCH][1024];   // 128 KB resident weights (chunks RCH..31)
  float gL[1024];        // 4 KB gates
  f16x2 hL2[128];        // 512 B h (fp16)
  float red[256];
};

template <bool F32, bool I64>
__device__ void ins_rec_impl(const int* ilen32, const int* bnd32,
                             const float* __restrict__ gx,
                             const uint4* __restrict__ pk,
                             const void* wlin, const void* blin,
                             float* __restrict__ out, int B, InsSmem& sm) {
  const int b = blockIdx.x, t = threadIdx.x;
  const int j = t >> 8, rr = t & 255;
  const int len = ldi<I64>(ilen32, b);
  const long n0 = (long)ldi<I64>(bnd32, b);
#pragma unroll
  for (int cc = 0; cc < LCH; ++cc)
    sm.wL[cc][t] = pk[((RCH + cc) * 4 + j) * 256 + rr];
  uint4 wr[RCH];
#pragma unroll
  for (int cg = 0; cg < RCH; ++cg)
    wr[cg] = pk[(cg * 4 + j) * 256 + rr];
  if (t < 128) {
    f16x2 z; z.x = (_Float16)0.f; z.y = (_Float16)0.f;
    sm.hL2[t] = z;
  }
  float c = 0.f, h = 0.f;
  __syncthreads();

  for (int m = 0; m < len; ++m) {
    float g0 = 0.f, g1 = 0.f, g2 = 0.f, g3 = 0.f;
    if (t < 256) {
      const float* gp = gx + (size_t)(n0 + m) * G4;
      g0 = gp[t]; g1 = gp[256 + t]; g2 = gp[512 + t]; g3 = gp[768 + t];
    }
    float a0 = 0.f, a1 = 0.f;
#pragma unroll
    for (int cg = 0; cg < RCH; ++cg) {
      float4 hv = ((const float4*)sm.hL2)[cg];
      if (cg & 1) a1 = dot8h(wr[cg], hv, a1);
      else        a0 = dot8h(wr[cg], hv, a0);
    }
#pragma unroll
    for (int cc = 0; cc < LCH; ++cc) {
      float4 hv = ((const float4*)sm.hL2)[RCH + cc];
      if (cc & 1) a1 = dot8h(sm.wL[cc][t], hv, a1);
      else        a0 = dot8h(sm.wL[cc][t], hv, a0);
    }
    sm.gL[t] = a0 + a1;
    __syncthreads();
    if (t < 256) {
      float gi = g0 + sm.gL[t];
      float gf = g1 + sm.gL[256 + t];
      float gg = g2 + sm.gL[512 + t];
      float go = g3 + sm.gL[768 + t];
      float si = sigm(gi), sf = sigm(gf), tg = tanhf(gg), so = sigm(go);
      c = sf * c + si * tg;
      h = so * tanhf(c);
      ((_Float16*)sm.hL2)[t] = (_Float16)h;
    }
    __syncthreads();
  }
  if (t < 256) sm.red[t] = h * ldf<F32>(wlin, t);
  __syncthreads();
  for (int st = 128; st > 0; st >>= 1) {
    if (t < st) sm.red[t] += sm.red[t + st];
    __syncthreads();
  }
  if (t == 0) out[b] = sm.red[0] + ldf<F32>(blin, 0);
}

__global__ __launch_bounds__(1024) void k_ins_rec(
    const int* ilen32, const int* bnd32, const float* __restrict__ gx,
    const uint4* __restrict__ pk, const void* wlin, const void* blin,
    float* __restrict__ out, int B, const void* fprobe, const int* iprobe) {
  __shared__ InsSmem sm;
  __shared__ int sfl;
  if (threadIdx.x == 0)
    sfl = (is_f32(fprobe) ? 1 : 0) | ((iprobe[1] == 0) ? 2 : 0);
  __syncthreads();
  const int fl = sfl;
  if (fl == 0)      ins_rec_impl<false, false>(ilen32, bnd32, gx, pk, wlin, blin, out, B, sm);
  else if (fl == 1) ins_rec_impl<true,  false>(ilen32, bnd32, gx, pk, wlin, blin, out, B, sm);
  else if (fl == 2) ins_rec_impl<false, true >(ilen32, bnd32, gx, pk, wlin, blin, out, B, sm);
  else              ins_rec_impl<true,  true >(ilen32, bnd32, gx, pk, wlin, blin, out, B, sm);
}

// ===== fallback (no gx workspace): fp32, 4 blocks per WG =====
#define IBB 4
struct InsSmemFB {
  float hL[IBB][HDIM];
  float xL[IBB][HDIM];
  float gL[IBB][G4];
};

template <bool F32, bool I64>
__device__ void ins_fb_impl(const int* ilen32, const int* bnd32,
                            const float* __restrict__ instrH,
                            const float* __restrict__ wTih,
                            const float* __restrict__ wThh,
                            const void* bih, const void* bhh,
                            const void* wlin, const void* blin,
                            float* __restrict__ out, int B, InsSmemFB& sm) {
  const int wg = blockIdx.x, t = threadIdx.x;
  const int myblk = t >> 8, myelem = t & 255;
  int len[IBB], n0[IBB];
#pragma unroll
  for (int i = 0; i < IBB; ++i) {
    int b = wg * IBB + i;
    len[i] = (b < B) ? ldi<I64>(ilen32, b) : 0;
    n0[i]  = (b < B) ? ldi<I64>(bnd32, b) : 0;
  }
  float c = 0.f;
  sm.hL[myblk][myelem] = 0.f;
  float bias_r = ldf<F32>(bih, t) + ldf<F32>(bhh, t);
  __syncthreads();
  int maxlen = 0;
#pragma unroll
  for (int i = 0; i < IBB; ++i) maxlen = max(maxlen, len[i]);
  for (int m = 0; m < maxlen; ++m) {
    unsigned act = 0;
#pragma unroll
    for (int i = 0; i < IBB; ++i) if (m < len[i]) act |= (1u << i);
    if (m < len[myblk])
      sm.xL[myblk][myelem] = instrH[(size_t)(n0[myblk] + m) * HDIM + myelem];
    __syncthreads();
    float a[IBB];
#pragma unroll
    for (int i = 0; i < IBB; ++i) a[i] = (act & (1u << i)) ? bias_r : 0.f;
    for (int k4 = 0; k4 < 64; ++k4) {
      float w0 = wThh[(size_t)(k4 * 4 + 0) * 1024 + t];
      float w1 = wThh[(size_t)(k4 * 4 + 1) * 1024 + t];
      float w2 = wThh[(size_t)(k4 * 4 + 2) * 1024 + t];
      float w3 = wThh[(size_t)(k4 * 4 + 3) * 1024 + t];
      float u0 = wTih[(size_t)(k4 * 4 + 0) * 1024 + t];
      float u1 = wTih[(size_t)(k4 * 4 + 1) * 1024 + t];
      float u2 = wTih[(size_t)(k4 * 4 + 2) * 1024 + t];
      float u3 = wTih[(size_t)(k4 * 4 + 3) * 1024 + t];
#pragma unroll
      for (int i = 0; i < IBB; ++i) {
        if (!(act & (1u << i))) continue;
        float4 h4 = *(const float4*)&sm.hL[i][k4 * 4];
        float4 x4 = *(const float4*)&sm.xL[i][k4 * 4];
        a[i] = fmaf(h4.x, w0, fmaf(h4.y, w1, fmaf(h4.z, w2, fmaf(h4.w, w3, a[i]))));
        a[i] = fmaf(x4.x, u0, fmaf(x4.y, u1, fmaf(x4.z, u2, fmaf(x4.w, u3, a[i]))));
      }
    }
#pragma unroll
    for (int i = 0; i < IBB; ++i)
      if (act & (1u << i)) sm.gL[i][t] = a[i];
    __syncthreads();
    if (m < len[myblk]) {
      float si = sigm(sm.gL[myblk][myelem]);
      float sf = sigm(sm.gL[myblk][256 + myelem]);
      float tg = tanhf(sm.gL[myblk][512 + myelem]);
      float so = sigm(sm.gL[myblk][768 + myelem]);
      c = sf * c + si * tg;
      sm.hL[myblk][myelem] = so * tanhf(c);
    }
    __syncthreads();
  }
  sm.gL[myblk][myelem] = sm.hL[myblk][myelem] * ldf<F32>(wlin, myelem);
  __syncthreads();
  for (int st = 128; st > 0; st >>= 1) {
    if (myelem < st) sm.gL[myblk][myelem] += sm.gL[myblk][myelem + st];
    __syncthreads();
  }
  if (myelem == 0 && wg * IBB + myblk < B)
    out[wg * IBB + myblk] = sm.gL[myblk][0] + ldf<F32>(blin, 0);
}

__global__ __launch_bounds__(1024) void k_ins_fb(
    const int* ilen32, const int* bnd32, const float* __restrict__ instrH,
    const float* __restrict__ wTih, const float* __restrict__ wThh,
    const void* bih, const void* bhh, const void* wlin, const void* blin,
    float* __restrict__ out, int B, const void* fprobe, const int* iprobe) {
  __shared__ InsSmemFB sm;
  __shared__ int sfl;
  if (threadIdx.x == 0)
    sfl = (is_f32(fprobe) ? 1 : 0) | ((iprobe[1] == 0) ? 2 : 0);
  __syncthreads();
  const int fl = sfl;
  if (fl == 0)      ins_fb_impl<false, false>(ilen32, bnd32, instrH, wTih, wThh, bih, bhh, wlin, blin, out, B, sm);
  else if (fl == 1) ins_fb_impl<true,  false>(ilen32, bnd32, instrH, wTih, wThh, bih, bhh, wlin, blin, out, B, sm);
  else if (fl == 2) ins_fb_impl<false, true >(ilen32, bnd32, instrH, wTih, wThh, bih, bhh, wlin, blin, out, B, sm);
  else              ins_fb_impl<true,  true >(ilen32, bnd32, instrH, wTih, wThh, bih, bhh, wlin, blin, out, B, sm);
}

extern "C" void kernel_launch(void* const* d_in, const int* in_sizes, int n_in,
                              void* d_out, int out_size, void* d_ws, size_t ws_size,
                              hipStream_t stream) {
  const int N = in_sizes[1];   // total instructions
  const int B = in_sizes[2];   // basic blocks

  // ---- workspace layout (float units) ----
  float* ws = (float*)d_ws;
  size_t off = 0;
  f16x4* tabi4 = (f16x4*)(ws + off); off += (size_t)VSZ * G4 / 2;  // 4 MB fp16
  float* instrH   = ws + off; off += (size_t)N * HDIM;
  float* wT_ihT   = ws + off; off += 262144;               // w_ih_tok^T fp32
  float* wT_ihI   = ws + off; off += 262144;               // w_ih_ins^T fp32 (gx + fb)
  float* wT_hhI   = ws + off; off += 262144;               // w_hh_ins^T fp32 (fb)
  f16x8* pkB_tok  = (f16x8*)(ws + off); off += 131072;     // MFMA B-frag w_hh_tok
  uint4* pk_ins   = (uint4*)(ws + off); off += 131072;     // row-gang fp16 w_hh_ins
  int*   permI    = (int*)(ws + off);
  off += ((size_t)N + 15) & ~(size_t)15;
  float* gx       = ws + off;
  const size_t need_gx = (off + (size_t)N * G4) * sizeof(float);
  const bool has_gx = (ws_size >= need_gx);

  const void* fprobe = d_in[5];              // w_ih_tok
  const int*  iprobe = (const int*)d_in[1];  // token_lengths

  hipLaunchKernelGGL(k_transp, dim3(32, 8), dim3(256), 0, stream, d_in[5], wT_ihT, fprobe);
  hipLaunchKernelGGL(k_transp, dim3(32, 8), dim3(256), 0, stream, d_in[9], wT_ihI, fprobe);
  hipLaunchKernelGGL(k_transp, dim3(32, 8), dim3(256), 0, stream, d_in[10], wT_hhI, fprobe);
  hipLaunchKernelGGL(k_packB, dim3(128), dim3(256), 0, stream, d_in[6], pkB_tok, fprobe);
  hipLaunchKernelGGL(k_pack, dim3(128), dim3(256), 0, stream, d_in[10], pk_ins, fprobe);

  hipLaunchKernelGGL(k_tok_table, dim3(VSZ / 16), dim3(256), 0, stream,
                     d_in[4], wT_ihT, d_in[7], d_in[8], tabi4, fprobe);
  hipLaunchKernelGGL(k_bucket, dim3(1), dim3(1024), 0, stream,
                     (const int*)d_in[1], N, permI, iprobe);
  hipLaunchKernelGGL(k_tok_lstm, dim3((N + IB - 1) / IB), dim3(256), 0, stream,
                     (const int*)d_in[0], (const int*)d_in[1], permI, tabi4,
                     pkB_tok, instrH, N, iprobe);
  if (has_gx) {
    hipLaunchKernelGGL(k_gx, dim3((N + 15) / 16), dim3(256), 0, stream,
                       instrH, wT_ihI, d_in[11], d_in[12], gx, N, fprobe);
    hipLaunchKernelGGL(k_ins_rec, dim3(B), dim3(1024), 0, stream,
                       (const int*)d_in[2], (const int*)d_in[3], gx, pk_ins,
                       d_in[13], d_in[14], (float*)d_out, B, fprobe, iprobe);
  } else {
    hipLaunchKernelGGL(k_ins_fb, dim3((B + IBB - 1) / IBB), dim3(1024), 0, stream,
                       (const int*)d_in[2], (const int*)d_in[3], instrH,
                       wT_ihI, wT_hhI, d_in[11], d_in[12], d_in[13], d_in[14],
                       (float*)d_out, B, fprobe, iprobe);
  }
}

// Round 16
// 961.527 us; speedup vs baseline: 2.2437x; 2.2437x over previous
//
#include <hip/hip_runtime.h>
#include <hip/hip_bf16.h>
#include <math.h>

#define VSZ 2048
#define EDIM 256
#define HDIM 256
#define G4 1024   // 4*H
#define TMAX 16
#define IB 16     // instructions per workgroup in token-LSTM (MFMA M=16)

typedef _Float16 f16x2 __attribute__((ext_vector_type(2)));
typedef _Float16 f16x4 __attribute__((ext_vector_type(4)));
typedef _Float16 f16x8 __attribute__((ext_vector_type(8)));
typedef float f32x4 __attribute__((ext_vector_type(4)));

#define HA_STRIDE 264   // fp16 elems per hA row (256 + 8 pad)
#define GW_STRIDE 260   // fp32 elems per gateW row (256 + 4 pad)

__device__ __forceinline__ float sigm(float x) { return 1.0f / (1.0f + expf(-x)); }

__device__ __forceinline__ float fdot2(f16x2 a, f16x2 b, float c) {
#if defined(__has_builtin) && __has_builtin(__builtin_amdgcn_fdot2)
  return __builtin_amdgcn_fdot2(a, b, c, false);
#else
  return c + (float)a.x * (float)b.x + (float)a.y * (float)b.y;
#endif
}

__device__ __forceinline__ float dot8h(uint4 w, float4 hv, float acc) {
  f16x2 h0 = __builtin_bit_cast(f16x2, hv.x);
  f16x2 h1 = __builtin_bit_cast(f16x2, hv.y);
  f16x2 h2 = __builtin_bit_cast(f16x2, hv.z);
  f16x2 h3 = __builtin_bit_cast(f16x2, hv.w);
  f16x2 w0 = __builtin_bit_cast(f16x2, w.x);
  f16x2 w1 = __builtin_bit_cast(f16x2, w.y);
  f16x2 w2 = __builtin_bit_cast(f16x2, w.z);
  f16x2 w3 = __builtin_bit_cast(f16x2, w.w);
  return fdot2(h3, w3, fdot2(h2, w2, fdot2(h1, w1, fdot2(h0, w0, acc))));
}

// ---- dtype probes ----
__device__ __forceinline__ bool is_f32(const void* w) {
  const unsigned short* p = (const unsigned short*)w;
  int pl = 0;
#pragma unroll
  for (int i = 0; i < 64; ++i) {
    unsigned e = (p[2 * i] >> 7) & 0xFF;
    pl += (e >= 113 && e <= 122) ? 1 : 0;
  }
  return pl < 48;
}

// ---- typed loads ----
template <bool F32>
__device__ __forceinline__ float ldf(const void* p, long j) {
  if (F32) return ((const float*)p)[j];
  return __uint_as_float(((unsigned)((const unsigned short*)p)[j]) << 16);
}
__device__ __forceinline__ float ldf_rt(const void* p, long j, bool f32) {
  if (f32) return ((const float*)p)[j];
  return __uint_as_float(((unsigned)((const unsigned short*)p)[j]) << 16);
}
template <bool I64>
__device__ __forceinline__ int ldi(const int* p, int j) {
  return I64 ? p[2 * j] : p[j];
}
__device__ __forceinline__ int ldi_rt(const int* p, int j, bool i64) {
  return i64 ? p[2 * j] : p[j];
}

// ===== fp32 transpose: dst[k*1024 + r] = src[r*256 + k] =====
__global__ __launch_bounds__(256) void k_transp(const void* src, float* __restrict__ dst,
                                                const void* fprobe) {
  __shared__ float tile[32][33];
  __shared__ int sf;
  if (threadIdx.x == 0) sf = is_f32(fprobe) ? 1 : 0;
  __syncthreads();
  const bool f32 = (sf != 0);
  const int tx = threadIdx.x & 31, ty = threadIdx.x >> 5;
  const int r0 = blockIdx.x * 32, c0 = blockIdx.y * 32;
#pragma unroll
  for (int q = 0; q < 4; ++q) {
    int rr = ty + q * 8;
    tile[rr][tx] = ldf_rt(src, (long)(r0 + rr) * 256 + (c0 + tx), f32);
  }
  __syncthreads();
#pragma unroll
  for (int q = 0; q < 4; ++q) {
    int cc = ty + q * 8;
    dst[(size_t)(c0 + cc) * 1024 + (r0 + tx)] = tile[tx][cc];
  }
}

// ===== fp16 weight packing (row-gang layout for k_ins_rec) =====
__global__ __launch_bounds__(256) void k_pack(const void* src, uint4* __restrict__ dst,
                                              const void* fprobe) {
  __shared__ int sf;
  if (threadIdx.x == 0) sf = is_f32(fprobe) ? 1 : 0;
  __syncthreads();
  const bool f32 = (sf != 0);
  const int idx = blockIdx.x * 256 + threadIdx.x;  // grid 128
  const int rr = idx & 255, j = (idx >> 8) & 3, c = idx >> 10;
  const long base = (long)(j * 256 + rr) * 256 + 8 * c;
  unsigned u[4];
#pragma unroll
  for (int q = 0; q < 4; ++q) {
    f16x2 v;
    v.x = (_Float16)ldf_rt(src, base + 2 * q, f32);
    v.y = (_Float16)ldf_rt(src, base + 2 * q + 1, f32);
    u[q] = __builtin_bit_cast(unsigned, v);
  }
  uint4 o; o.x = u[0]; o.y = u[1]; o.z = u[2]; o.w = u[3];
  dst[idx] = o;
}

// ===== MFMA B-fragment packing (gate col n = e*4 + j) =====
__global__ __launch_bounds__(256) void k_packB(const void* src, f16x8* __restrict__ dst,
                                               const void* fprobe) {
  __shared__ int sf;
  if (threadIdx.x == 0) sf = is_f32(fprobe) ? 1 : 0;
  __syncthreads();
  const bool f32 = (sf != 0);
  const int idx = blockIdx.x * 256 + threadIdx.x;  // 0..32767, grid 128
  const int l = idx & 63;
  int rest = idx >> 6;
  const int kt = rest & 7; rest >>= 3;
  const int nt = rest & 15;
  const int w = rest >> 4;
  const int n = 256 * w + nt * 16 + (l & 15);
  const int j = n & 3, e = n >> 2;
  const long base = (long)(j * 256 + e) * 256 + kt * 32 + ((l >> 4) << 3);
  f16x8 v;
#pragma unroll
  for (int q = 0; q < 8; ++q) v[q] = (_Float16)ldf_rt(src, base + q, f32);
  dst[idx] = v;
}

// ===== kernel 1: token gate table -> interleaved fp16x4 tab =====
template <bool F32>
__device__ void tok_table_impl(const void* emb, const float* __restrict__ wT,
                               const void* bih, const void* bhh,
                               f16x4* __restrict__ tabi4, float (*xs)[256]) {
  const int t = threadIdx.x;
  const int v0 = blockIdx.x * 16;
#pragma unroll
  for (int i = 0; i < 16; ++i) xs[i][t] = ldf<F32>(emb, (long)(v0 + i) * EDIM + t);
  __syncthreads();
  float acc[4][16];
#pragma unroll
  for (int j = 0; j < 4; ++j)
#pragma unroll
    for (int i = 0; i < 16; ++i) acc[j][i] = 0.f;
  for (int k4 = 0; k4 < 64; ++k4) {
    float w[4][4];
#pragma unroll
    for (int kk = 0; kk < 4; ++kk)
#pragma unroll
      for (int j = 0; j < 4; ++j)
        w[j][kk] = wT[(size_t)(k4 * 4 + kk) * 1024 + j * 256 + t];
#pragma unroll
    for (int i = 0; i < 16; ++i) {
      float4 h4 = *(const float4*)&xs[i][k4 * 4];
#pragma unroll
      for (int j = 0; j < 4; ++j)
        acc[j][i] = fmaf(h4.x, w[j][0], fmaf(h4.y, w[j][1],
                    fmaf(h4.z, w[j][2], fmaf(h4.w, w[j][3], acc[j][i]))));
    }
  }
  float b[4];
#pragma unroll
  for (int j = 0; j < 4; ++j)
    b[j] = ldf<F32>(bih, j * 256 + t) + ldf<F32>(bhh, j * 256 + t);
#pragma unroll
  for (int i = 0; i < 16; ++i) {
    f16x4 v;
    v.x = (_Float16)(acc[0][i] + b[0]);
    v.y = (_Float16)(acc[1][i] + b[1]);
    v.z = (_Float16)(acc[2][i] + b[2]);
    v.w = (_Float16)(acc[3][i] + b[3]);
    tabi4[(size_t)(v0 + i) * 256 + t] = v;
  }
}

__global__ __launch_bounds__(256) void k_tok_table(
    const void* emb, const float* __restrict__ wT, const void* bih,
    const void* bhh, f16x4* __restrict__ tabi4, const void* fprobe) {
  __shared__ float xs[16][256];
  __shared__ int sf;
  if (threadIdx.x == 0) sf = is_f32(fprobe) ? 1 : 0;
  __syncthreads();
  if (sf) tok_table_impl<true>(emb, wT, bih, bhh, tabi4, xs);
  else    tok_table_impl<false>(emb, wT, bih, bhh, tabi4, xs);
}

// ===== length bucketing: single WG, LDS atomics only =====
__global__ __launch_bounds__(1024) void k_bucket(const int* tlen, int N,
                                                 int* __restrict__ perm,
                                                 const int* iprobe) {
  __shared__ int cnt[17], base[17], cur[17];
  const int t = threadIdx.x;
  const bool i64 = (iprobe[1] == 0);
  if (t < 17) { cnt[t] = 0; cur[t] = 0; }
  __syncthreads();
  for (int n = t; n < N; n += 1024) {
    int len = ldi_rt(tlen, n, i64);
    len = max(0, min(16, len));
    atomicAdd(&cnt[len], 1);
  }
  __syncthreads();
  if (t == 0) {
    int s = 0;
    for (int i = 0; i <= 16; ++i) { base[i] = s; s += cnt[i]; }
  }
  __syncthreads();
  for (int n = t; n < N; n += 1024) {
    int len = ldi_rt(tlen, n, i64);
    len = max(0, min(16, len));
    int pos = base[len] + atomicAdd(&cur[len], 1);
    perm[pos] = n;
  }
}

// ===== kernel 2: token LSTM — MFMA 16x16x32 f16 (round-13 structure) =====
struct TokSmemM {
  float gateW[4][16 * GW_STRIDE];   // 66560 B: per-wave D staging (fp32)
  _Float16 hA[16 * HA_STRIDE];      // 8448 B: h in MFMA-A layout (fp16)
  int tokL[IB][TMAX];
  int lenL[IB];
  int nIdx[IB];
};

template <bool I64>
__device__ void tok_mfma_impl(const int* tok32, const int* tlen32,
                              const int* __restrict__ perm,
                              const f16x4* __restrict__ tabi4,
                              const f16x8* __restrict__ pkB,
                              float* __restrict__ instrH, int N, TokSmemM& sm) {
  const int n0 = blockIdx.x * IB, t = threadIdx.x;
  const int w = t >> 6, l = t & 63;
  if (t < IB) {
    int slot = n0 + t;
    int n = (slot < N) ? perm[slot] : -1;
    sm.nIdx[t] = n;
    sm.lenL[t] = (n >= 0) ? ldi<I64>(tlen32, n) : 0;
  }
  for (int idx = t; idx < 16 * HA_STRIDE / 2; idx += 256) ((unsigned*)sm.hA)[idx] = 0;
  __syncthreads();
  {
    int i = t >> 4, s = t & 15;
    int n = sm.nIdx[i];
    sm.tokL[i][s] = (n >= 0) ? ldi<I64>(tok32, n * TMAX + s) : 0;
  }
  float c[IB];
#pragma unroll
  for (int i = 0; i < IB; ++i) c[i] = 0.f;
  __syncthreads();
  int maxlen = 0;
#pragma unroll
  for (int i = 0; i < IB; ++i) maxlen = max(maxlen, sm.lenL[i]);

  const f16x8* Bp = pkB + (size_t)w * (16 * 8 * 64);
  const int aOff = (l & 15) * HA_STRIDE + ((l >> 4) << 3);
  const int m0 = (l >> 4) << 2;
  float* gw = sm.gateW[w];

  for (int s = 0; s < maxlen; ++s) {
    f16x8 aF[8];
#pragma unroll
    for (int kt = 0; kt < 8; ++kt)
      aF[kt] = *(const f16x8*)&sm.hA[aOff + kt * 32];
    // unroll 2: overlap two MFMA chains without spilling (budget 256 VGPR @ 2WG/CU)
#pragma unroll 2
    for (int g4 = 0; g4 < 4; ++g4) {
      f32x4 a0 = {0.f, 0.f, 0.f, 0.f}, a1 = a0, a2 = a0, a3 = a0;
#pragma unroll
      for (int kt = 0; kt < 8; ++kt) {
        const f16x8* bb = Bp + ((size_t)(g4 * 4) * 8 + kt) * 64 + l;
        f16x8 b0 = bb[0 * 8 * 64];
        f16x8 b1 = bb[1 * 8 * 64];
        f16x8 b2 = bb[2 * 8 * 64];
        f16x8 b3 = bb[3 * 8 * 64];
        a0 = __builtin_amdgcn_mfma_f32_16x16x32_f16(aF[kt], b0, a0, 0, 0, 0);
        a1 = __builtin_amdgcn_mfma_f32_16x16x32_f16(aF[kt], b1, a1, 0, 0, 0);
        a2 = __builtin_amdgcn_mfma_f32_16x16x32_f16(aF[kt], b2, a2, 0, 0, 0);
        a3 = __builtin_amdgcn_mfma_f32_16x16x32_f16(aF[kt], b3, a3, 0, 0, 0);
      }
      const int colb = (l & 15);
#pragma unroll
      for (int r = 0; r < 4; ++r) {
        gw[(m0 + r) * GW_STRIDE + (g4 * 4 + 0) * 16 + colb] = a0[r];
        gw[(m0 + r) * GW_STRIDE + (g4 * 4 + 1) * 16 + colb] = a1[r];
        gw[(m0 + r) * GW_STRIDE + (g4 * 4 + 2) * 16 + colb] = a2[r];
        gw[(m0 + r) * GW_STRIDE + (g4 * 4 + 3) * 16 + colb] = a3[r];
      }
    }
    __syncthreads();
    // epilogue: FULL unroll -> all 16 tab loads have static offsets, compiler
    // clusters them up front and interleaves vmcnt waits (no reg-array indexing)
#pragma unroll
    for (int m = 0; m < IB; ++m) {
      if (s < sm.lenL[m]) {
        float4 gv = *(const float4*)&gw[m * GW_STRIDE + 4 * l];
        f16x4 tb = tabi4[(size_t)sm.tokL[m][s] * 256 + t];
        float gi = gv.x + (float)tb.x;
        float gf = gv.y + (float)tb.y;
        float gg = gv.z + (float)tb.z;
        float go = gv.w + (float)tb.w;
        float si = sigm(gi), sf = sigm(gf), tg = tanhf(gg), so = sigm(go);
        c[m] = sf * c[m] + si * tg;
        sm.hA[m * HA_STRIDE + t] = (_Float16)(so * tanhf(c[m]));
      }
    }
    __syncthreads();
  }
#pragma unroll
  for (int m = 0; m < IB; ++m) {
    int n = sm.nIdx[m];
    if (n >= 0) instrH[(size_t)n * HDIM + t] = (float)sm.hA[m * HA_STRIDE + t];
  }
}

__global__ __launch_bounds__(256, 2) void k_tok_lstm(
    const int* tok32, const int* tlen32, const int* __restrict__ perm,
    const f16x4* __restrict__ tabi4, const f16x8* __restrict__ pkB,
    float* __restrict__ instrH, int N, const int* iprobe) {
  __shared__ TokSmemM sm;
  __shared__ int sfl;
  if (threadIdx.x == 0) sfl = (iprobe[1] == 0) ? 1 : 0;
  __syncthreads();
  if (sfl) tok_mfma_impl<true >(tok32, tlen32, perm, tabi4, pkB, instrH, N, sm);
  else     tok_mfma_impl<false>(tok32, tlen32, perm, tabi4, pkB, instrH, N, sm);
}

// ===== kernel 3a: gx GEMM (fp32) =====
template <bool F32>
__device__ void gx_impl(const float* __restrict__ instrH,
                        const float* __restrict__ wT, const void* bih,
                        const void* bhh, float* __restrict__ gx, int N,
                        float (*xs)[256]) {
  const int t = threadIdx.x;
  const int n0 = blockIdx.x * 16;
#pragma unroll
  for (int i = 0; i < 16; ++i) {
    int n = n0 + i;
    xs[i][t] = (n < N) ? instrH[(size_t)n * HDIM + t] : 0.f;
  }
  __syncthreads();
  float acc[4][16];
#pragma unroll
  for (int j = 0; j < 4; ++j)
#pragma unroll
    for (int i = 0; i < 16; ++i) acc[j][i] = 0.f;
  for (int k4 = 0; k4 < 64; ++k4) {
    float w[4][4];
#pragma unroll
    for (int kk = 0; kk < 4; ++kk)
#pragma unroll
      for (int j = 0; j < 4; ++j)
        w[j][kk] = wT[(size_t)(k4 * 4 + kk) * 1024 + j * 256 + t];
#pragma unroll
    for (int i = 0; i < 16; ++i) {
      float4 h4 = *(const float4*)&xs[i][k4 * 4];
#pragma unroll
      for (int j = 0; j < 4; ++j)
        acc[j][i] = fmaf(h4.x, w[j][0], fmaf(h4.y, w[j][1],
                    fmaf(h4.z, w[j][2], fmaf(h4.w, w[j][3], acc[j][i]))));
    }
  }
#pragma unroll
  for (int j = 0; j < 4; ++j) {
    const float bj = ldf<F32>(bih, j * 256 + t) + ldf<F32>(bhh, j * 256 + t);
#pragma unroll
    for (int i = 0; i < 16; ++i) {
      int n = n0 + i;
      if (n < N) gx[(size_t)n * G4 + j * 256 + t] = acc[j][i] + bj;
    }
  }
}

__global__ __launch_bounds__(256) void k_gx(
    const float* __restrict__ instrH, const float* __restrict__ wT,
    const void* bih, const void* bhh, float* __restrict__ gx, int N,
    const void* fprobe) {
  __shared__ float xs[16][256];
  __shared__ int sf;
  if (threadIdx.x == 0) sf = is_f32(fprobe) ? 1 : 0;
  __syncthreads();
  if (sf) gx_impl<true>(instrH, wT, bih, bhh, gx, N, xs);
  else    gx_impl<false>(instrH, wT, bih, bhh, gx, N, xs);
}

// ===== kernel 3b: instruction-LSTM — weights RESIDENT in regs+LDS =====
#define RCH 24   // chunks in registers
#define LCH 8    // chunks in LDS
struct InsSmem {
  uint4 wL[LCH][1024];   // 128 KB resident weights (chunks RCH..31)
  float gL[1024];        // 4 KB gates
  f16x2 hL2[128];        // 512 B h (fp16)
  float red[256];
};

template <bool F32, bool I64>
__device__ void ins_rec_impl(const int* ilen32, const int* bnd32,
                             const float* __restrict__ gx,
                             const uint4* __restrict__ pk,
                             const void* wlin, const void* blin,
                             float* __restrict__ out, int B, InsSmem& sm) {
  const int b = blockIdx.x, t = threadIdx.x;
  const int j = t >> 8, rr = t & 255;
  const int len = ldi<I64>(ilen32, b);
  const long n0 = (long)ldi<I64>(bnd32, b);
#pragma unroll
  for (int cc = 0; cc < LCH; ++cc)
    sm.wL[cc][t] = pk[((RCH + cc) * 4 + j) * 256 + rr];
  uint4 wr[RCH];
#pragma unroll
  for (int cg = 0; cg < RCH; ++cg)
    wr[cg] = pk[(cg * 4 + j) * 256 + rr];
  if (t < 128) {
    f16x2 z; z.x = (_Float16)0.f; z.y = (_Float16)0.f;
    sm.hL2[t] = z;
  }
  float c = 0.f, h = 0.f;
  __syncthreads();

  for (int m = 0; m < len; ++m) {
    float g0 = 0.f, g1 = 0.f, g2 = 0.f, g3 = 0.f;
    if (t < 256) {
      const float* gp = gx + (size_t)(n0 + m) * G4;
      g0 = gp[t]; g1 = gp[256 + t]; g2 = gp[512 + t]; g3 = gp[768 + t];
    }
    float a0 = 0.f, a1 = 0.f;
#pragma unroll
    for (int cg = 0; cg < RCH; ++cg) {
      float4 hv = ((const float4*)sm.hL2)[cg];
      if (cg & 1) a1 = dot8h(wr[cg], hv, a1);
      else        a0 = dot8h(wr[cg], hv, a0);
    }
#pragma unroll
    for (int cc = 0; cc < LCH; ++cc) {
      float4 hv = ((const float4*)sm.hL2)[RCH + cc];
      if (cc & 1) a1 = dot8h(sm.wL[cc][t], hv, a1);
      else        a0 = dot8h(sm.wL[cc][t], hv, a0);
    }
    sm.gL[t] = a0 + a1;
    __syncthreads();
    if (t < 256) {
      float gi = g0 + sm.gL[t];
      float gf = g1 + sm.gL[256 + t];
      float gg = g2 + sm.gL[512 + t];
      float go = g3 + sm.gL[768 + t];
      float si = sigm(gi), sf = sigm(gf), tg = tanhf(gg), so = sigm(go);
      c = sf * c + si * tg;
      h = so * tanhf(c);
      ((_Float16*)sm.hL2)[t] = (_Float16)h;
    }
    __syncthreads();
  }
  if (t < 256) sm.red[t] = h * ldf<F32>(wlin, t);
  __syncthreads();
  for (int st = 128; st > 0; st >>= 1) {
    if (t < st) sm.red[t] += sm.red[t + st];
    __syncthreads();
  }
  if (t == 0) out[b] = sm.red[0] + ldf<F32>(blin, 0);
}

__global__ __launch_bounds__(1024) void k_ins_rec(
    const int* ilen32, const int* bnd32, const float* __restrict__ gx,
    const uint4* __restrict__ pk, const void* wlin, const void* blin,
    float* __restrict__ out, int B, const void* fprobe, const int* iprobe) {
  __shared__ InsSmem sm;
  __shared__ int sfl;
  if (threadIdx.x == 0)
    sfl = (is_f32(fprobe) ? 1 : 0) | ((iprobe[1] == 0) ? 2 : 0);
  __syncthreads();
  const int fl = sfl;
  if (fl == 0)      ins_rec_impl<false, false>(ilen32, bnd32, gx, pk, wlin, blin, out, B, sm);
  else if (fl == 1) ins_rec_impl<true,  false>(ilen32, bnd32, gx, pk, wlin, blin, out, B, sm);
  else if (fl == 2) ins_rec_impl<false, true >(ilen32, bnd32, gx, pk, wlin, blin, out, B, sm);
  else              ins_rec_impl<true,  true >(ilen32, bnd32, gx, pk, wlin, blin, out, B, sm);
}

// ===== fallback (no gx workspace): fp32, 4 blocks per WG =====
#define IBB 4
struct InsSmemFB {
  float hL[IBB][HDIM];
  float xL[IBB][HDIM];
  float gL[IBB][G4];
};

template <bool F32, bool I64>
__device__ void ins_fb_impl(const int* ilen32, const int* bnd32,
                            const float* __restrict__ instrH,
                            const float* __restrict__ wTih,
                            const float* __restrict__ wThh,
                            const void* bih, const void* bhh,
                            const void* wlin, const void* blin,
                            float* __restrict__ out, int B, InsSmemFB& sm) {
  const int wg = blockIdx.x, t = threadIdx.x;
  const int myblk = t >> 8, myelem = t & 255;
  int len[IBB], n0[IBB];
#pragma unroll
  for (int i = 0; i < IBB; ++i) {
    int b = wg * IBB + i;
    len[i] = (b < B) ? ldi<I64>(ilen32, b) : 0;
    n0[i]  = (b < B) ? ldi<I64>(bnd32, b) : 0;
  }
  float c = 0.f;
  sm.hL[myblk][myelem] = 0.f;
  float bias_r = ldf<F32>(bih, t) + ldf<F32>(bhh, t);
  __syncthreads();
  int maxlen = 0;
#pragma unroll
  for (int i = 0; i < IBB; ++i) maxlen = max(maxlen, len[i]);
  for (int m = 0; m < maxlen; ++m) {
    unsigned act = 0;
#pragma unroll
    for (int i = 0; i < IBB; ++i) if (m < len[i]) act |= (1u << i);
    if (m < len[myblk])
      sm.xL[myblk][myelem] = instrH[(size_t)(n0[myblk] + m) * HDIM + myelem];
    __syncthreads();
    float a[IBB];
#pragma unroll
    for (int i = 0; i < IBB; ++i) a[i] = (act & (1u << i)) ? bias_r : 0.f;
    for (int k4 = 0; k4 < 64; ++k4) {
      float w0 = wThh[(size_t)(k4 * 4 + 0) * 1024 + t];
      float w1 = wThh[(size_t)(k4 * 4 + 1) * 1024 + t];
      float w2 = wThh[(size_t)(k4 * 4 + 2) * 1024 + t];
      float w3 = wThh[(size_t)(k4 * 4 + 3) * 1024 + t];
      float u0 = wTih[(size_t)(k4 * 4 + 0) * 1024 + t];
      float u1 = wTih[(size_t)(k4 * 4 + 1) * 1024 + t];
      float u2 = wTih[(size_t)(k4 * 4 + 2) * 1024 + t];
      float u3 = wTih[(size_t)(k4 * 4 + 3) * 1024 + t];
#pragma unroll
      for (int i = 0; i < IBB; ++i) {
        if (!(act & (1u << i))) continue;
        float4 h4 = *(const float4*)&sm.hL[i][k4 * 4];
        float4 x4 = *(const float4*)&sm.xL[i][k4 * 4];
        a[i] = fmaf(h4.x, w0, fmaf(h4.y, w1, fmaf(h4.z, w2, fmaf(h4.w, w3, a[i]))));
        a[i] = fmaf(x4.x, u0, fmaf(x4.y, u1, fmaf(x4.z, u2, fmaf(x4.w, u3, a[i]))));
      }
    }
#pragma unroll
    for (int i = 0; i < IBB; ++i)
      if (act & (1u << i)) sm.gL[i][t] = a[i];
    __syncthreads();
    if (m < len[myblk]) {
      float si = sigm(sm.gL[myblk][myelem]);
      float sf = sigm(sm.gL[myblk][256 + myelem]);
      float tg = tanhf(sm.gL[myblk][512 + myelem]);
      float so = sigm(sm.gL[myblk][768 + myelem]);
      c = sf * c + si * tg;
      sm.hL[myblk][myelem] = so * tanhf(c);
    }
    __syncthreads();
  }
  sm.gL[myblk][myelem] = sm.hL[myblk][myelem] * ldf<F32>(wlin, myelem);
  __syncthreads();
  for (int st = 128; st > 0; st >>= 1) {
    if (myelem < st) sm.gL[myblk][myelem] += sm.gL[myblk][myelem + st];
    __syncthreads();
  }
  if (myelem == 0 && wg * IBB + myblk < B)
    out[wg * IBB + myblk] = sm.gL[myblk][0] + ldf<F32>(blin, 0);
}

__global__ __launch_bounds__(1024) void k_ins_fb(
    const int* ilen32, const int* bnd32, const float* __restrict__ instrH,
    const float* __restrict__ wTih, const float* __restrict__ wThh,
    const void* bih, const void* bhh, const void* wlin, const void* blin,
    float* __restrict__ out, int B, const void* fprobe, const int* iprobe) {
  __shared__ InsSmemFB sm;
  __shared__ int sfl;
  if (threadIdx.x == 0)
    sfl = (is_f32(fprobe) ? 1 : 0) | ((iprobe[1] == 0) ? 2 : 0);
  __syncthreads();
  const int fl = sfl;
  if (fl == 0)      ins_fb_impl<false, false>(ilen32, bnd32, instrH, wTih, wThh, bih, bhh, wlin, blin, out, B, sm);
  else if (fl == 1) ins_fb_impl<true,  false>(ilen32, bnd32, instrH, wTih, wThh, bih, bhh, wlin, blin, out, B, sm);
  else if (fl == 2) ins_fb_impl<false, true >(ilen32, bnd32, instrH, wTih, wThh, bih, bhh, wlin, blin, out, B, sm);
  else              ins_fb_impl<true,  true >(ilen32, bnd32, instrH, wTih, wThh, bih, bhh, wlin, blin, out, B, sm);
}

extern "C" void kernel_launch(void* const* d_in, const int* in_sizes, int n_in,
                              void* d_out, int out_size, void* d_ws, size_t ws_size,
                              hipStream_t stream) {
  const int N = in_sizes[1];   // total instructions
  const int B = in_sizes[2];   // basic blocks

  // ---- workspace layout (float units) ----
  float* ws = (float*)d_ws;
  size_t off = 0;
  f16x4* tabi4 = (f16x4*)(ws + off); off += (size_t)VSZ * G4 / 2;  // 4 MB fp16
  float* instrH   = ws + off; off += (size_t)N * HDIM;
  float* wT_ihT   = ws + off; off += 262144;               // w_ih_tok^T fp32
  float* wT_ihI   = ws + off; off += 262144;               // w_ih_ins^T fp32 (gx + fb)
  float* wT_hhI   = ws + off; off += 262144;               // w_hh_ins^T fp32 (fb)
  f16x8* pkB_tok  = (f16x8*)(ws + off); off += 131072;     // MFMA B-frag w_hh_tok
  uint4* pk_ins   = (uint4*)(ws + off); off += 131072;     // row-gang fp16 w_hh_ins
  int*   permI    = (int*)(ws + off);
  off += ((size_t)N + 15) & ~(size_t)15;
  float* gx       = ws + off;
  const size_t need_gx = (off + (size_t)N * G4) * sizeof(float);
  const bool has_gx = (ws_size >= need_gx);

  const void* fprobe = d_in[5];              // w_ih_tok
  const int*  iprobe = (const int*)d_in[1];  // token_lengths

  hipLaunchKernelGGL(k_transp, dim3(32, 8), dim3(256), 0, stream, d_in[5], wT_ihT, fprobe);
  hipLaunchKernelGGL(k_transp, dim3(32, 8), dim3(256), 0, stream, d_in[9], wT_ihI, fprobe);
  hipLaunchKernelGGL(k_transp, dim3(32, 8), dim3(256), 0, stream, d_in[10], wT_hhI, fprobe);
  hipLaunchKernelGGL(k_packB, dim3(128), dim3(256), 0, stream, d_in[6], pkB_tok, fprobe);
  hipLaunchKernelGGL(k_pack, dim3(128), dim3(256), 0, stream, d_in[10], pk_ins, fprobe);

  hipLaunchKernelGGL(k_tok_table, dim3(VSZ / 16), dim3(256), 0, stream,
                     d_in[4], wT_ihT, d_in[7], d_in[8], tabi4, fprobe);
  hipLaunchKernelGGL(k_bucket, dim3(1), dim3(1024), 0, stream,
                     (const int*)d_in[1], N, permI, iprobe);
  hipLaunchKernelGGL(k_tok_lstm, dim3((N + IB - 1) / IB), dim3(256), 0, stream,
                     (const int*)d_in[0], (const int*)d_in[1], permI, tabi4,
                     pkB_tok, instrH, N, iprobe);
  if (has_gx) {
    hipLaunchKernelGGL(k_gx, dim3((N + 15) / 16), dim3(256), 0, stream,
                       instrH, wT_ihI, d_in[11], d_in[12], gx, N, fprobe);
    hipLaunchKernelGGL(k_ins_rec, dim3(B), dim3(1024), 0, stream,
                       (const int*)d_in[2], (const int*)d_in[3], gx, pk_ins,
                       d_in[13], d_in[14], (float*)d_out, B, fprobe, iprobe);
  } else {
    hipLaunchKernelGGL(k_ins_fb, dim3((B + IBB - 1) / IBB), dim3(1024), 0, stream,
                       (const int*)d_in[2], (const int*)d_in[3], instrH,
                       wT_ihI, wT_hhI, d_in[11], d_in[12], d_in[13], d_in[14],
                       (float*)d_out, B, fprobe, iprobe);
  }
}